// Round 10
// baseline (211.882 us; speedup 1.0000x reference)
//
#include <hip/hip_runtime.h>
#include <hip/hip_bf16.h>

#define EPSV  1e-5f
// C^-0.5 * log2(e): softmax then uses exp2 directly
#define QSC   0.0901684400555650f

typedef __attribute__((ext_vector_type(8)))  __bf16 bfrag;   // MFMA A/B operand
typedef __attribute__((ext_vector_type(4)))  float  f32x4;
typedef __attribute__((ext_vector_type(8)))  short  s16x8;
typedef __attribute__((ext_vector_type(4)))  short  s16x4;

static __device__ __forceinline__ short f2b(float f) {
    __hip_bfloat16 h = __float2bfloat16(f);
    return __builtin_bit_cast(short, h);
}

// async global->LDS, 16B per lane; LDS dest = wave-uniform base + lane*16
#define GLDS16(SRC, DST) __builtin_amdgcn_global_load_lds( \
    (__attribute__((address_space(1))) void*)(SRC),        \
    (__attribute__((address_space(3))) void*)(DST), 16, 0, 0)

// ---------------------------------------------------------------------------
// K1: GroupNorm partial sums (blocks 0..255)  +  weight transpose to bf16
//     (blocks 256..1279) fused into one launch.
// ---------------------------------------------------------------------------
__global__ __launch_bounds__(256) void gn_part_prep(const float* __restrict__ x,
                                                    float* __restrict__ part,
                                                    const float* __restrict__ wq,
                                                    const float* __restrict__ wk,
                                                    const float* __restrict__ wv,
                                                    const float* __restrict__ wo,
                                                    short* __restrict__ wt) {
    if (blockIdx.x >= 256) {
        const int bb = blockIdx.x - 256;
        const int z = bb >> 8;
        const int n = bb & 255;
        const int k = threadIdx.x;
        const float* w = (z == 0) ? wq : (z == 1) ? wk : (z == 2) ? wv : wo;
        wt[(z * 256 + n) * 256 + k] = f2b(w[k * 256 + n]);
        return;
    }
    const int b = blockIdx.x >> 3, ch = blockIdx.x & 7;
    const int t = threadIdx.x;
    const int c4 = t & 63;
    const int rr = t >> 6;
    float s1 = 0.f, s2 = 0.f;
    for (int i = 0; i < 32; ++i) {
        const int pos = ch * 128 + rr + (i << 2);
        const f32x4 v = *reinterpret_cast<const f32x4*>(x + (((b << 10) + pos) << 8) + (c4 << 2));
        s1 += v[0] + v[1] + v[2] + v[3];
        s2 += v[0]*v[0] + v[1]*v[1] + v[2]*v[2] + v[3]*v[3];
    }
    __shared__ float ls1[256], ls2[256];
    ls1[t] = s1; ls2[t] = s2;
    __syncthreads();
    if (t < 32) {
        float a1 = 0.f, a2 = 0.f;
        for (int r2 = 0; r2 < 4; ++r2)
            for (int e = 0; e < 2; ++e) {
                const int idx = r2 * 64 + t * 2 + e;
                a1 += ls1[idx]; a2 += ls2[idx];
            }
        part[((b * 8 + ch) * 32 + t) * 2 + 0] = a1;
        part[((b * 8 + ch) * 32 + t) * 2 + 1] = a2;
    }
}

// ---------------------------------------------------------------------------
// K2: fused GN-finalize + GN-normalize + QKV projection.
// ---------------------------------------------------------------------------
__global__ __launch_bounds__(256) void qkv_gemm(const float* __restrict__ x,
                                                const float* __restrict__ part,
                                                const float* __restrict__ gns,
                                                const float* __restrict__ gnb,
                                                const short* __restrict__ wt,
                                                const float* __restrict__ bq,
                                                const float* __restrict__ bk,
                                                const float* __restrict__ bv,
                                                short* __restrict__ qo,
                                                short* __restrict__ ko,
                                                short* __restrict__ vtg) {
    __shared__ short At[64][264];
    __shared__ float gmean[32], grstd[32];
    __shared__ float sA[256], sB[256];

    const int t  = threadIdx.x;
    const int m0 = blockIdx.x * 64;
    const int b  = m0 >> 10;
    const int lane = t & 63, w = t >> 6;
    const int lr = lane & 15, lh = lane >> 4;

    if (t < 32) {
        float s1 = 0.f, s2 = 0.f;
        for (int ch = 0; ch < 8; ++ch) {
            s1 += part[((b * 8 + ch) * 32 + t) * 2 + 0];
            s2 += part[((b * 8 + ch) * 32 + t) * 2 + 1];
        }
        const float mean = s1 * (1.f / 8192.f);
        const float var  = s2 * (1.f / 8192.f) - mean * mean;
        gmean[t] = mean;
        grstd[t] = rsqrtf(var + EPSV);
    }
    __syncthreads();
    {
        const float a = grstd[t >> 3] * gns[t];
        sA[t] = a;
        sB[t] = gnb[t] - gmean[t >> 3] * a;
    }
    __syncthreads();

    {
        const int r = t >> 2, q4 = t & 3;
        const float* xrow = x + (m0 + r) * 256;
        for (int i = 0; i < 16; ++i) {
            const int c0 = (q4 + 4 * i) * 4;
            const f32x4 v  = *reinterpret_cast<const f32x4*>(xrow + c0);
            const f32x4 aa = *reinterpret_cast<const f32x4*>(&sA[c0]);
            const f32x4 bb = *reinterpret_cast<const f32x4*>(&sB[c0]);
            s16x4 o;
            for (int j = 0; j < 4; ++j) o[j] = f2b(v[j] * aa[j] + bb[j]);
            *reinterpret_cast<s16x4*>(&At[r][c0]) = o;
        }
    }
    __syncthreads();

    for (int z = 0; z < 3; ++z) {
        f32x4 acc[4][4];
        for (int mi = 0; mi < 4; ++mi)
            for (int ni = 0; ni < 4; ++ni) acc[mi][ni] = (f32x4){0.f, 0.f, 0.f, 0.f};
        const short* wz = wt + z * 65536 + (w * 64 + lr) * 256 + lh * 8;
#pragma unroll
        for (int kt = 0; kt < 8; ++kt) {
            bfrag bf[4];
#pragma unroll
            for (int ni = 0; ni < 4; ++ni)
                bf[ni] = *reinterpret_cast<const bfrag*>(wz + ni * 4096 + kt * 32);
            bfrag af[4];
#pragma unroll
            for (int mi = 0; mi < 4; ++mi)
                af[mi] = *reinterpret_cast<const bfrag*>(&At[mi * 16 + lr][kt * 32 + lh * 8]);
#pragma unroll
            for (int ni = 0; ni < 4; ++ni)
#pragma unroll
                for (int mi = 0; mi < 4; ++mi)
                    acc[mi][ni] = __builtin_amdgcn_mfma_f32_16x16x32_bf16(af[mi], bf[ni], acc[mi][ni], 0, 0, 0);
        }
        if (z == 2) {
            for (int ni = 0; ni < 4; ++ni) {
                const int col = w * 64 + ni * 16 + lr;
                const float bb = bv[col];
                for (int mi = 0; mi < 4; ++mi) {
                    const int pos = (m0 & 1023) + mi * 16 + lh * 4;
                    s16x4 ov;
                    for (int j = 0; j < 4; ++j) ov[j] = f2b(acc[mi][ni][j] + bb);
                    *reinterpret_cast<s16x4*>(&vtg[(((b << 8) + col) << 10) + pos]) = ov;
                }
            }
        } else {
            short* outp = (z == 0) ? qo : ko;
            const float* bias = (z == 0) ? bq : bk;
            const float s = (z == 0) ? QSC : 1.0f;
            for (int ni = 0; ni < 4; ++ni) {
                const int col = w * 64 + ni * 16 + lr;
                const float bsc = bias[col] * s;
                for (int mi = 0; mi < 4; ++mi) {
                    const int row = m0 + mi * 16 + lh * 4;
                    for (int j = 0; j < 4; ++j)
                        outp[(row + j) * 256 + col] = f2b(acc[mi][ni][j] * s + bsc);
                }
            }
        }
    }
}

// ---------------------------------------------------------------------------
// K3: flash attention, 2 INDEPENDENT BLOCKS PER CU.
// 4 waves (256 thr) x 16 q-rows = QBLK 64; KVBLK=32 double-buffered;
// LDS 68 KB -> 2 blocks/CU (grid 512) = 8 waves/CU, un-barrier-coupled
// across blocks so phases (MFMA / softmax / staging) overlap between blocks.
// K: [32][256] rows XOR-swizzled (8 granules, key r&7).
// V: superrow layout — 2 d-rows per 128B superrow, 8 granules, XOR s&7.
// P: per-wave [16 q][32 k], 4 granules, XOR lr&3.
// ---------------------------------------------------------------------------
__global__ __launch_bounds__(256) void attn(const short* __restrict__ qq,
                                            const short* __restrict__ kk,
                                            const short* __restrict__ vt,
                                            short* __restrict__ ao) {
    __shared__ __align__(1024) short Kt[2][32 * 256];   // 2 x 16 KB
    __shared__ __align__(1024) short Vt[2][128 * 64];   // 2 x 16 KB (superrows)
    __shared__ __align__(1024) short Pl[4][16 * 32];    // 4 KB

    int bid = blockIdx.x;
    bid = ((bid & 7) << 6) | (bid >> 3);   // XCD swizzle: 64 blocks/XCD
    const int b = bid >> 4, qt = bid & 15;
    const int t = threadIdx.x;
    const int w = t >> 6, lane = t & 63;
    const int lr = lane & 15, lh = lane >> 4;
    const int qr0 = qt * 64 + w * 16;
    const int sw3 = lr & 7;                // K swizzle key
    const int sw2 = lr & 3;                // P swizzle key

    // Q fragments (B-operand): qf[ks] = Q[q=lr][k=ks*32+lh*8..], pre-scaled
    bfrag qf[8];
    {
        const short* qp = qq + (((b << 10) + qr0 + lr) << 8) + lh * 8;
#pragma unroll
        for (int ks = 0; ks < 8; ++ks)
            qf[ks] = *reinterpret_cast<const bfrag*>(qp + ks * 32);
    }

    const short* kbase = kk + ((long)b << 18);
    const short* vbase = vt + ((long)b << 18);
    short* plw = Pl[w];

    // per-wave staging: K rows w*8..+7 (4 calls x 2 rows)
    auto stageK = [&](int kt_, int buf) {
#pragma unroll
        for (int t2 = 0; t2 < 4; ++t2) {
            const int rbase = w * 8 + t2 * 2;
            const int r  = rbase + (lane >> 5);
            const int gs = (lane & 31) ^ (r & 7);
            GLDS16(kbase + ((kt_ * 32 + r) << 8) + (gs << 3), &Kt[buf][rbase << 8]);
        }
    };
    // per-wave staging: V superrows w*32..+31 (4 calls x 8 superrows)
    auto stageV = [&](int kt_, int buf) {
#pragma unroll
        for (int t2 = 0; t2 < 4; ++t2) {
            const int sbase = w * 32 + t2 * 8;
            const int s   = sbase + (lane >> 3);
            const int ggp = lane & 7;
            const int gg  = ggp ^ (s & 7);
            const int d   = (s << 1) + (gg >> 2);
            const int g   = gg & 3;
            GLDS16(vbase + (d << 10) + kt_ * 32 + (g << 3), &Vt[buf][sbase << 6]);
        }
    };

    f32x4 o[16];
#pragma unroll
    for (int ci = 0; ci < 16; ++ci) o[ci] = (f32x4){0.f, 0.f, 0.f, 0.f};
    float mv = -3e38f, ls = 0.f;   // per-lane (q=lr) state, lazy lsum

    stageK(0, 0); stageV(0, 0);    // 8 loads in flight per thread

    for (int kt = 0; kt < 32; ++kt) {
        const int cur = kt & 1;
        __asm__ volatile("s_barrier" ::: "memory");
        if (kt < 31) {
            stageK(kt + 1, cur ^ 1);
            stageV(kt + 1, cur ^ 1);
            __asm__ volatile("s_waitcnt vmcnt(8)" ::: "memory");
        } else {
            __asm__ volatile("s_waitcnt vmcnt(0)" ::: "memory");
        }
        __asm__ volatile("s_barrier" ::: "memory");

        // ---- S^T = K . Q : sacc[ni] = S[key=ni*16+lh*4+j][q=lr]
        f32x4 sacc[2];
        sacc[0] = (f32x4){0.f, 0.f, 0.f, 0.f};
        sacc[1] = (f32x4){0.f, 0.f, 0.f, 0.f};
        __builtin_amdgcn_s_setprio(1);
#pragma unroll
        for (int ks = 0; ks < 8; ++ks) {
#pragma unroll
            for (int ni = 0; ni < 2; ++ni) {
                const int row = ni * 16 + lr;
                const bfrag kf = *reinterpret_cast<const bfrag*>(
                    &Kt[cur][(row << 8) + ((((ks << 2) + lh) ^ sw3) << 3)]);
                sacc[ni] = __builtin_amdgcn_mfma_f32_16x16x32_bf16(kf, qf[ks], sacc[ni], 0, 0, 0);
            }
        }
        __builtin_amdgcn_s_setprio(0);

        // ---- online softmax (base-2), per-lane q-row = lr
        float rm = fmaxf(fmaxf(sacc[0][0], sacc[0][1]), fmaxf(sacc[0][2], sacc[0][3]));
        rm = fmaxf(rm, fmaxf(fmaxf(sacc[1][0], sacc[1][1]), fmaxf(sacc[1][2], sacc[1][3])));
        rm = fmaxf(rm, __shfl_xor(rm, 16));
        rm = fmaxf(rm, __shfl_xor(rm, 32));

        const bool grow = __any(rm > mv);
        const float mn = grow ? fmaxf(mv, rm) : mv;
        float p[2][4];
        float rs = 0.f;
#pragma unroll
        for (int ni = 0; ni < 2; ++ni)
#pragma unroll
            for (int r2 = 0; r2 < 4; ++r2) {
                p[ni][r2] = exp2f(sacc[ni][r2] - mn);
                rs += p[ni][r2];
            }

        // ---- stage P early: row q=lr (32 shorts), granule gc, XOR sw2
#pragma unroll
        for (int ni = 0; ni < 2; ++ni) {
            s16x4 pw;
#pragma unroll
            for (int r2 = 0; r2 < 4; ++r2) pw[r2] = f2b(p[ni][r2]);
            const int gc = (ni << 1) + (lh >> 1);
            const int ad = (lr << 5) + ((gc ^ sw2) << 3) + ((lh & 1) << 2);
            *reinterpret_cast<s16x4*>(&plw[ad]) = pw;
        }

        if (grow) {
            const float sc = exp2f(mv - mn);
            mv = mn;
            ls = ls * sc + rs;
            float scb[4];
#pragma unroll
            for (int j = 0; j < 4; ++j) scb[j] = __shfl(sc, lh * 4 + j);
#pragma unroll
            for (int ci = 0; ci < 16; ++ci)
#pragma unroll
                for (int j = 0; j < 4; ++j) o[ci][j] *= scb[j];
        } else {
            ls += rs;
        }

        // pa = P[q=lr][k=lh*8..+7]  (granule lh, XOR sw2)
        const bfrag pa = *reinterpret_cast<const bfrag*>(
            &plw[(lr << 5) + ((lh ^ sw2) << 3)]);

        // ---- O += P . V   (V via superrow layout)
        __builtin_amdgcn_s_setprio(1);
#pragma unroll
        for (int ci = 0; ci < 16; ++ci) {
            const int d   = (ci << 4) + lr;
            const int s   = d >> 1;
            const int gg  = ((d & 1) << 2) | lh;
            const int ggp = gg ^ (s & 7);
            const bfrag va = *reinterpret_cast<const bfrag*>(
                &Vt[cur][(s << 6) + (ggp << 3)]);
            o[ci] = __builtin_amdgcn_mfma_f32_16x16x32_bf16(pa, va, o[ci], 0, 0, 0);
        }
        __builtin_amdgcn_s_setprio(0);
    }

    // lazy lsum reduction across the 4 lane-copies of each q-row
    ls += __shfl_xor(ls, 16);
    ls += __shfl_xor(ls, 32);

    float invb[4];
#pragma unroll
    for (int j = 0; j < 4; ++j) invb[j] = 1.0f / __shfl(ls, lh * 4 + j);
#pragma unroll
    for (int j = 0; j < 4; ++j) {
        const int row = (b << 10) + qr0 + lh * 4 + j;
        for (int ci = 0; ci < 16; ++ci)
            ao[(row << 8) + (ci << 4) + lr] = f2b(o[ci][j] * invb[j]);
    }
}

// ---------------------------------------------------------------------------
// K4: output projection + bias + residual.  B direct from global (L2-hot).
// ---------------------------------------------------------------------------
__global__ __launch_bounds__(256) void oproj(const short* __restrict__ ao,
                                             const short* __restrict__ wto,
                                             const float* __restrict__ bo,
                                             const float* __restrict__ x,
                                             float* __restrict__ out) {
    __shared__ short At[64][264];

    const int t  = threadIdx.x;
    const int m0 = blockIdx.x * 64;
    const int lane = t & 63, w = t >> 6;
    const int lr = lane & 15, lh = lane >> 4;

    {
        const int r = t >> 2, q4 = t & 3;
        const short* ap = ao + (m0 + r) * 256;
        for (int i = 0; i < 8; ++i) {
            const int c0 = (q4 + 4 * i) * 8;
            *reinterpret_cast<s16x8*>(&At[r][c0]) = *reinterpret_cast<const s16x8*>(ap + c0);
        }
    }
    __syncthreads();

    f32x4 acc[4][4];
    for (int mi = 0; mi < 4; ++mi)
        for (int ni = 0; ni < 4; ++ni) acc[mi][ni] = (f32x4){0.f, 0.f, 0.f, 0.f};

    const short* wz = wto + (w * 64 + lr) * 256 + lh * 8;
#pragma unroll
    for (int kt = 0; kt < 8; ++kt) {
        bfrag bf[4];
#pragma unroll
        for (int ni = 0; ni < 4; ++ni)
            bf[ni] = *reinterpret_cast<const bfrag*>(wz + ni * 4096 + kt * 32);
        bfrag af[4];
#pragma unroll
        for (int mi = 0; mi < 4; ++mi)
            af[mi] = *reinterpret_cast<const bfrag*>(&At[mi * 16 + lr][kt * 32 + lh * 8]);
#pragma unroll
        for (int ni = 0; ni < 4; ++ni)
#pragma unroll
            for (int mi = 0; mi < 4; ++mi)
                acc[mi][ni] = __builtin_amdgcn_mfma_f32_16x16x32_bf16(af[mi], bf[ni], acc[mi][ni], 0, 0, 0);
    }

    for (int ni = 0; ni < 4; ++ni) {
        const int col = w * 64 + ni * 16 + lr;
        const float bb = bo[col];
        for (int mi = 0; mi < 4; ++mi) {
            const int row = m0 + mi * 16 + lh * 4;
            for (int j = 0; j < 4; ++j) {
                const int idx = (row + j) * 256 + col;
                out[idx] = acc[mi][ni][j] + bb + x[idx];
            }
        }
    }
}

// ---------------------------------------------------------------------------
extern "C" void kernel_launch(void* const* d_in, const int* in_sizes, int n_in,
                              void* d_out, int out_size, void* d_ws, size_t ws_size,
                              hipStream_t stream) {
    const float* x   = (const float*)d_in[0];
    const float* gns = (const float*)d_in[1];
    const float* gnb = (const float*)d_in[2];
    const float* Wq  = (const float*)d_in[3];
    const float* bq  = (const float*)d_in[4];
    const float* Wk  = (const float*)d_in[5];
    const float* bk  = (const float*)d_in[6];
    const float* Wv  = (const float*)d_in[7];
    const float* bv  = (const float*)d_in[8];
    const float* Wo  = (const float*)d_in[9];
    const float* bo  = (const float*)d_in[10];
    float* out = (float*)d_out;

    char* ws = (char*)d_ws;
    short* wt   = (short*)(ws);
    float* part = (float*)(ws + 524288);
    const size_t MB16 = 16777216;
    short* qb  = (short*)(ws + (1 << 20));
    short* kb  = (short*)(ws + (1 << 20) + MB16);
    short* vtb = (short*)(ws + (1 << 20) + 2 * MB16);
    short* aob = (short*)(ws + (1 << 20) + 3 * MB16);

    hipLaunchKernelGGL(gn_part_prep, dim3(1280), dim3(256), 0, stream,
                       x, part, Wq, Wk, Wv, Wo, wt);
    hipLaunchKernelGGL(qkv_gemm, dim3(512), dim3(256), 0, stream,
                       x, part, gns, gnb, wt, bq, bk, bv, qb, kb, vtb);
    hipLaunchKernelGGL(attn, dim3(512), dim3(256), 0, stream, qb, kb, vtb, aob);
    hipLaunchKernelGGL(oproj, dim3(512), dim3(256), 0, stream,
                       aob, wt + 3 * 65536, bo, x, out);
}

// Round 11
// 156.484 us; speedup vs baseline: 1.3540x; 1.3540x over previous
//
#include <hip/hip_runtime.h>
#include <hip/hip_bf16.h>

#define EPSV  1e-5f
// C^-0.5 * log2(e): softmax then uses exp2 directly
#define QSC   0.0901684400555650f

typedef __attribute__((ext_vector_type(8)))  __bf16 bfrag;   // MFMA A/B operand
typedef __attribute__((ext_vector_type(4)))  float  f32x4;
typedef __attribute__((ext_vector_type(16))) float  f32x16;  // 32x32 MFMA C/D
typedef __attribute__((ext_vector_type(8)))  short  s16x8;
typedef __attribute__((ext_vector_type(4)))  short  s16x4;

static __device__ __forceinline__ short f2b(float f) {
    __hip_bfloat16 h = __float2bfloat16(f);
    return __builtin_bit_cast(short, h);
}

// async global->LDS, 16B per lane; LDS dest = wave-uniform base + lane*16
#define GLDS16(SRC, DST) __builtin_amdgcn_global_load_lds( \
    (__attribute__((address_space(1))) void*)(SRC),        \
    (__attribute__((address_space(3))) void*)(DST), 16, 0, 0)

// ---------------------------------------------------------------------------
// K1: GroupNorm partial sums (blocks 0..255)  +  weight transpose to bf16
//     (blocks 256..1279) fused into one launch.
// ---------------------------------------------------------------------------
__global__ __launch_bounds__(256) void gn_part_prep(const float* __restrict__ x,
                                                    float* __restrict__ part,
                                                    const float* __restrict__ wq,
                                                    const float* __restrict__ wk,
                                                    const float* __restrict__ wv,
                                                    const float* __restrict__ wo,
                                                    short* __restrict__ wt) {
    if (blockIdx.x >= 256) {
        const int bb = blockIdx.x - 256;
        const int z = bb >> 8;
        const int n = bb & 255;
        const int k = threadIdx.x;
        const float* w = (z == 0) ? wq : (z == 1) ? wk : (z == 2) ? wv : wo;
        wt[(z * 256 + n) * 256 + k] = f2b(w[k * 256 + n]);
        return;
    }
    const int b = blockIdx.x >> 3, ch = blockIdx.x & 7;
    const int t = threadIdx.x;
    const int c4 = t & 63;
    const int rr = t >> 6;
    float s1 = 0.f, s2 = 0.f;
    for (int i = 0; i < 32; ++i) {
        const int pos = ch * 128 + rr + (i << 2);
        const f32x4 v = *reinterpret_cast<const f32x4*>(x + (((b << 10) + pos) << 8) + (c4 << 2));
        s1 += v[0] + v[1] + v[2] + v[3];
        s2 += v[0]*v[0] + v[1]*v[1] + v[2]*v[2] + v[3]*v[3];
    }
    __shared__ float ls1[256], ls2[256];
    ls1[t] = s1; ls2[t] = s2;
    __syncthreads();
    if (t < 32) {
        float a1 = 0.f, a2 = 0.f;
        for (int r2 = 0; r2 < 4; ++r2)
            for (int e = 0; e < 2; ++e) {
                const int idx = r2 * 64 + t * 2 + e;
                a1 += ls1[idx]; a2 += ls2[idx];
            }
        part[((b * 8 + ch) * 32 + t) * 2 + 0] = a1;
        part[((b * 8 + ch) * 32 + t) * 2 + 1] = a2;
    }
}

// ---------------------------------------------------------------------------
// K2: fused GN-finalize + GN-normalize + QKV projection.
// ---------------------------------------------------------------------------
__global__ __launch_bounds__(256) void qkv_gemm(const float* __restrict__ x,
                                                const float* __restrict__ part,
                                                const float* __restrict__ gns,
                                                const float* __restrict__ gnb,
                                                const short* __restrict__ wt,
                                                const float* __restrict__ bq,
                                                const float* __restrict__ bk,
                                                const float* __restrict__ bv,
                                                short* __restrict__ qo,
                                                short* __restrict__ ko,
                                                short* __restrict__ vtg) {
    __shared__ short At[64][264];
    __shared__ float gmean[32], grstd[32];
    __shared__ float sA[256], sB[256];

    const int t  = threadIdx.x;
    const int m0 = blockIdx.x * 64;
    const int b  = m0 >> 10;
    const int lane = t & 63, w = t >> 6;
    const int lr = lane & 15, lh = lane >> 4;

    if (t < 32) {
        float s1 = 0.f, s2 = 0.f;
        for (int ch = 0; ch < 8; ++ch) {
            s1 += part[((b * 8 + ch) * 32 + t) * 2 + 0];
            s2 += part[((b * 8 + ch) * 32 + t) * 2 + 1];
        }
        const float mean = s1 * (1.f / 8192.f);
        const float var  = s2 * (1.f / 8192.f) - mean * mean;
        gmean[t] = mean;
        grstd[t] = rsqrtf(var + EPSV);
    }
    __syncthreads();
    {
        const float a = grstd[t >> 3] * gns[t];
        sA[t] = a;
        sB[t] = gnb[t] - gmean[t >> 3] * a;
    }
    __syncthreads();

    {
        const int r = t >> 2, q4 = t & 3;
        const float* xrow = x + (m0 + r) * 256;
        for (int i = 0; i < 16; ++i) {
            const int c0 = (q4 + 4 * i) * 4;
            const f32x4 v  = *reinterpret_cast<const f32x4*>(xrow + c0);
            const f32x4 aa = *reinterpret_cast<const f32x4*>(&sA[c0]);
            const f32x4 bb = *reinterpret_cast<const f32x4*>(&sB[c0]);
            s16x4 o;
            for (int j = 0; j < 4; ++j) o[j] = f2b(v[j] * aa[j] + bb[j]);
            *reinterpret_cast<s16x4*>(&At[r][c0]) = o;
        }
    }
    __syncthreads();

    for (int z = 0; z < 3; ++z) {
        f32x4 acc[4][4];
        for (int mi = 0; mi < 4; ++mi)
            for (int ni = 0; ni < 4; ++ni) acc[mi][ni] = (f32x4){0.f, 0.f, 0.f, 0.f};
        const short* wz = wt + z * 65536 + (w * 64 + lr) * 256 + lh * 8;
#pragma unroll
        for (int kt = 0; kt < 8; ++kt) {
            bfrag bf[4];
#pragma unroll
            for (int ni = 0; ni < 4; ++ni)
                bf[ni] = *reinterpret_cast<const bfrag*>(wz + ni * 4096 + kt * 32);
            bfrag af[4];
#pragma unroll
            for (int mi = 0; mi < 4; ++mi)
                af[mi] = *reinterpret_cast<const bfrag*>(&At[mi * 16 + lr][kt * 32 + lh * 8]);
#pragma unroll
            for (int ni = 0; ni < 4; ++ni)
#pragma unroll
                for (int mi = 0; mi < 4; ++mi)
                    acc[mi][ni] = __builtin_amdgcn_mfma_f32_16x16x32_bf16(af[mi], bf[ni], acc[mi][ni], 0, 0, 0);
        }
        if (z == 2) {
            for (int ni = 0; ni < 4; ++ni) {
                const int col = w * 64 + ni * 16 + lr;
                const float bb = bv[col];
                for (int mi = 0; mi < 4; ++mi) {
                    const int pos = (m0 & 1023) + mi * 16 + lh * 4;
                    s16x4 ov;
                    for (int j = 0; j < 4; ++j) ov[j] = f2b(acc[mi][ni][j] + bb);
                    *reinterpret_cast<s16x4*>(&vtg[(((b << 8) + col) << 10) + pos]) = ov;
                }
            }
        } else {
            short* outp = (z == 0) ? qo : ko;
            const float* bias = (z == 0) ? bq : bk;
            const float s = (z == 0) ? QSC : 1.0f;
            for (int ni = 0; ni < 4; ++ni) {
                const int col = w * 64 + ni * 16 + lr;
                const float bsc = bias[col] * s;
                for (int mi = 0; mi < 4; ++mi) {
                    const int row = m0 + mi * 16 + lh * 4;
                    for (int j = 0; j < 4; ++j)
                        outp[(row + j) * 256 + col] = f2b(acc[mi][ni][j] * s + bsc);
                }
            }
        }
    }
}

// ---------------------------------------------------------------------------
// K3: flash attention, 32x32 MFMA + d-split wave pairs.
// 8 waves (512 thr), QBLK=128: q-group = w&3 (32 q-rows), d-half = w>>2.
// Pair waves (w, w+4) duplicate QK^T+softmax (no sync) and each computes
// 128 of the 256 output dims -> per-CU LDS reads drop 528->416 b128/iter
// while every read feeds a 32x32 MFMA (2x FLOP/read vs 16x16).
// P is shared per q-group: both pair waves write IDENTICAL values (benign
// race; 2 barriers separate any read from the next overwrite).
// Double-buffered K/V via global_load_lds + counted vmcnt(8) (r5 staging).
// 32x32 layouts verified in r9: C/D col=lane&31, row=(r&3)+8*(r>>2)+4*(lane>>5).
// ---------------------------------------------------------------------------
__global__ __launch_bounds__(512, 2) void attn(const short* __restrict__ qq,
                                               const short* __restrict__ kk,
                                               const short* __restrict__ vt,
                                               short* __restrict__ ao) {
    __shared__ __align__(1024) short Kt[2][64 * 256];   // 2 x 32 KB
    __shared__ __align__(1024) short Vt[2][256 * 64];   // 2 x 32 KB
    __shared__ __align__(1024) short Pl[4][32 * 64];    // 16 KB (per q-group)

    int bid = blockIdx.x;
    bid = ((bid & 7) << 5) | (bid >> 3);   // XCD swizzle: 4 batches/XCD in L2
    const int b = bid >> 3, qt = bid & 7;
    const int t = threadIdx.x;
    const int w = t >> 6, lane = t & 63;
    const int q  = lane & 31;              // this lane's q-row (within group)
    const int h  = lane >> 5;              // k-half selector
    const int qs = q & 7;                  // swizzle key
    const int qg = w & 3;                  // q-group
    const int dh = w >> 2;                 // d-half (0: d<128, 1: d>=128)
    const int qr0 = qt * 128 + qg * 32;

    // Q fragments as MFMA B-operand: qf[ks] -> Q[q][k=ks*16 + h*8 + j]
    bfrag qf[16];
    {
        const short* qp = qq + (((b << 10) + qr0 + q) << 8) + (h << 3);
#pragma unroll
        for (int ks = 0; ks < 16; ++ks)
            qf[ks] = *reinterpret_cast<const bfrag*>(qp + (ks << 4));
    }

    const short* kbase = kk + ((long)b << 18);
    const short* vbase = vt + ((long)b << 18);
    short* plw = Pl[qg];

    // staging split across 8 waves (r5): K rows w*8..+7, V rows w*32..+31
    auto stageK = [&](int kt_, int buf) {
#pragma unroll
        for (int t2 = 0; t2 < 4; ++t2) {
            const int rbase = w * 8 + t2 * 2;
            const int r  = rbase + (lane >> 5);
            const int gs = (lane & 31) ^ (r & 7);
            GLDS16(kbase + ((kt_ * 64 + r) << 8) + (gs << 3), &Kt[buf][rbase << 8]);
        }
    };
    auto stageV = [&](int kt_, int buf) {
#pragma unroll
        for (int t2 = 0; t2 < 4; ++t2) {
            const int rbase = w * 32 + t2 * 8;
            const int r  = rbase + (lane >> 3);
            const int gs = (lane & 7) ^ (r & 7);
            GLDS16(vbase + (r << 10) + kt_ * 64 + (gs << 3), &Vt[buf][rbase << 6]);
        }
    };

    f32x16 o[4];                           // 4 x 32-d tiles = this wave's 128 d
#pragma unroll
    for (int dt = 0; dt < 4; ++dt)
#pragma unroll
        for (int j = 0; j < 16; ++j) o[dt][j] = 0.f;
    float mv = -3e38f, ls = 0.f;           // per-lane (q-row) softmax state

    stageK(0, 0); stageV(0, 0);            // 8 loads in flight per thread

    for (int kt = 0; kt < 16; ++kt) {
        const int cur = kt & 1;
        __asm__ volatile("s_barrier" ::: "memory");
        if (kt < 15) {
            stageK(kt + 1, cur ^ 1);
            stageV(kt + 1, cur ^ 1);
            __asm__ volatile("s_waitcnt vmcnt(8)" ::: "memory");
        } else {
            __asm__ volatile("s_waitcnt vmcnt(0)" ::: "memory");
        }
        __asm__ volatile("s_barrier" ::: "memory");

        // ---- S^T = K . Q : sacc[kt2] = S[key=kt2*32+rowmap][q]
        f32x16 sacc[2];
#pragma unroll
        for (int kt2 = 0; kt2 < 2; ++kt2)
#pragma unroll
            for (int j = 0; j < 16; ++j) sacc[kt2][j] = 0.f;
        __builtin_amdgcn_s_setprio(1);
#pragma unroll
        for (int ks = 0; ks < 16; ++ks) {
            const int G = (ks << 1) + h;
#pragma unroll
            for (int kt2 = 0; kt2 < 2; ++kt2) {
                const int arow = kt2 * 32 + q;
                const bfrag ka = *reinterpret_cast<const bfrag*>(
                    &Kt[cur][(arow << 8) + ((G ^ qs) << 3)]);
                sacc[kt2] = __builtin_amdgcn_mfma_f32_32x32x16_bf16(ka, qf[ks], sacc[kt2], 0, 0, 0);
            }
        }
        __builtin_amdgcn_s_setprio(0);

        // ---- online softmax (base-2); lane holds 32 of 64 keys for its q
        float rm = sacc[0][0];
#pragma unroll
        for (int j = 1; j < 16; ++j) rm = fmaxf(rm, sacc[0][j]);
#pragma unroll
        for (int j = 0; j < 16; ++j) rm = fmaxf(rm, sacc[1][j]);
        rm = fmaxf(rm, __shfl_xor(rm, 32));

        const bool grow = __any(rm > mv);
        const float mn = grow ? fmaxf(mv, rm) : mv;
        float rs = 0.f;
        // P = exp2(S - mn) staged to shared per-group LDS (both pair waves
        // write identical values). reg r of tile kt2 -> key = kt2*32 +
        // (r&3) + 8*(r>>2) + 4*h.
#pragma unroll
        for (int kt2 = 0; kt2 < 2; ++kt2)
#pragma unroll
            for (int grp = 0; grp < 4; ++grp) {
                s16x4 pw;
#pragma unroll
                for (int j = 0; j < 4; ++j) {
                    const float v = exp2f(sacc[kt2][grp * 4 + j] - mn);
                    rs += v;
                    pw[j] = f2b(v);
                }
                const int g = (kt2 << 2) + grp;
                const int ad = (q << 6) + ((g ^ qs) << 3) + (h << 2);
                *reinterpret_cast<s16x4*>(&plw[ad]) = pw;
            }

        if (grow) {
            const float sc = exp2f(mv - mn);
            mv = mn;
            ls = ls * sc + rs;
#pragma unroll
            for (int dt = 0; dt < 4; ++dt) o[dt] *= sc;
        } else {
            ls += rs;
        }

        // ---- O^T += V^T . P over this wave's d-half
        __builtin_amdgcn_s_setprio(1);
#pragma unroll
        for (int kf = 0; kf < 4; ++kf) {
            const int gp = (kf << 1) + h;
            const bfrag pb = *reinterpret_cast<const bfrag*>(
                &plw[(q << 6) + ((gp ^ qs) << 3)]);
#pragma unroll
            for (int dt = 0; dt < 4; ++dt) {
                const int vrow = (dh * 4 + dt) * 32 + q;
                const bfrag va = *reinterpret_cast<const bfrag*>(
                    &Vt[cur][(vrow << 6) + ((gp ^ qs) << 3)]);
                o[dt] = __builtin_amdgcn_mfma_f32_32x32x16_bf16(va, pb, o[dt], 0, 0, 0);
            }
        }
        __builtin_amdgcn_s_setprio(0);
    }

    // lane pair (l, l^32) holds disjoint key-halves' partial sums
    ls += __shfl_xor(ls, 32);
    const float inv = 1.0f / ls;

    // store this wave's 128-d half: d = (dh*4+dt)*32 + grp*8 + 4h + j
    {
        short* aop = ao + ((((b << 10) + qr0 + q)) << 8) + (h << 2);
#pragma unroll
        for (int dt = 0; dt < 4; ++dt)
#pragma unroll
            for (int grp = 0; grp < 4; ++grp) {
                s16x4 ov;
#pragma unroll
                for (int j = 0; j < 4; ++j) ov[j] = f2b(o[dt][grp * 4 + j] * inv);
                *reinterpret_cast<s16x4*>(&aop[(dh * 4 + dt) * 32 + grp * 8]) = ov;
            }
    }
}

// ---------------------------------------------------------------------------
// K4: output projection + bias + residual.  B direct from global (L2-hot).
// ---------------------------------------------------------------------------
__global__ __launch_bounds__(256) void oproj(const short* __restrict__ ao,
                                             const short* __restrict__ wto,
                                             const float* __restrict__ bo,
                                             const float* __restrict__ x,
                                             float* __restrict__ out) {
    __shared__ short At[64][264];

    const int t  = threadIdx.x;
    const int m0 = blockIdx.x * 64;
    const int lane = t & 63, w = t >> 6;
    const int lr = lane & 15, lh = lane >> 4;

    {
        const int r = t >> 2, q4 = t & 3;
        const short* ap = ao + (m0 + r) * 256;
        for (int i = 0; i < 8; ++i) {
            const int c0 = (q4 + 4 * i) * 8;
            *reinterpret_cast<s16x8*>(&At[r][c0]) = *reinterpret_cast<const s16x8*>(ap + c0);
        }
    }
    __syncthreads();

    f32x4 acc[4][4];
    for (int mi = 0; mi < 4; ++mi)
        for (int ni = 0; ni < 4; ++ni) acc[mi][ni] = (f32x4){0.f, 0.f, 0.f, 0.f};

    const short* wz = wto + (w * 64 + lr) * 256 + lh * 8;
#pragma unroll
    for (int kt = 0; kt < 8; ++kt) {
        bfrag bf[4];
#pragma unroll
        for (int ni = 0; ni < 4; ++ni)
            bf[ni] = *reinterpret_cast<const bfrag*>(wz + ni * 4096 + kt * 32);
        bfrag af[4];
#pragma unroll
        for (int mi = 0; mi < 4; ++mi)
            af[mi] = *reinterpret_cast<const bfrag*>(&At[mi * 16 + lr][kt * 32 + lh * 8]);
#pragma unroll
        for (int ni = 0; ni < 4; ++ni)
#pragma unroll
            for (int mi = 0; mi < 4; ++mi)
                acc[mi][ni] = __builtin_amdgcn_mfma_f32_16x16x32_bf16(af[mi], bf[ni], acc[mi][ni], 0, 0, 0);
    }

    for (int ni = 0; ni < 4; ++ni) {
        const int col = w * 64 + ni * 16 + lr;
        const float bb = bo[col];
        for (int mi = 0; mi < 4; ++mi) {
            const int row = m0 + mi * 16 + lh * 4;
            for (int j = 0; j < 4; ++j) {
                const int idx = (row + j) * 256 + col;
                out[idx] = acc[mi][ni][j] + bb + x[idx];
            }
        }
    }
}

// ---------------------------------------------------------------------------
extern "C" void kernel_launch(void* const* d_in, const int* in_sizes, int n_in,
                              void* d_out, int out_size, void* d_ws, size_t ws_size,
                              hipStream_t stream) {
    const float* x   = (const float*)d_in[0];
    const float* gns = (const float*)d_in[1];
    const float* gnb = (const float*)d_in[2];
    const float* Wq  = (const float*)d_in[3];
    const float* bq  = (const float*)d_in[4];
    const float* Wk  = (const float*)d_in[5];
    const float* bk  = (const float*)d_in[6];
    const float* Wv  = (const float*)d_in[7];
    const float* bv  = (const float*)d_in[8];
    const float* Wo  = (const float*)d_in[9];
    const float* bo  = (const float*)d_in[10];
    float* out = (float*)d_out;

    char* ws = (char*)d_ws;
    short* wt   = (short*)(ws);
    float* part = (float*)(ws + 524288);
    const size_t MB16 = 16777216;
    short* qb  = (short*)(ws + (1 << 20));
    short* kb  = (short*)(ws + (1 << 20) + MB16);
    short* vtb = (short*)(ws + (1 << 20) + 2 * MB16);
    short* aob = (short*)(ws + (1 << 20) + 3 * MB16);

    hipLaunchKernelGGL(gn_part_prep, dim3(1280), dim3(256), 0, stream,
                       x, part, Wq, Wk, Wv, Wo, wt);
    hipLaunchKernelGGL(qkv_gemm, dim3(512), dim3(256), 0, stream,
                       x, part, gns, gnb, wt, bq, bk, bv, qb, kb, vtb);
    hipLaunchKernelGGL(attn, dim3(256), dim3(512), 0, stream, qb, kb, vtb, aob);
    hipLaunchKernelGGL(oproj, dim3(512), dim3(256), 0, stream,
                       aob, wt + 3 * 65536, bo, x, out);
}

// Round 12
// 130.734 us; speedup vs baseline: 1.6207x; 1.1970x over previous
//
#include <hip/hip_runtime.h>
#include <hip/hip_bf16.h>

#define EPSV  1e-5f
#define QSC   0.0625f     // C^-0.5 (natural-exp softmax)

typedef __attribute__((ext_vector_type(8))) __bf16 bfrag;   // MFMA A/B operand
typedef __attribute__((ext_vector_type(4))) float  f32x4;
typedef __attribute__((ext_vector_type(8))) short  s16x8;
typedef __attribute__((ext_vector_type(4))) short  s16x4;

static __device__ __forceinline__ short f2b(float f) {
    __hip_bfloat16 h = __float2bfloat16(f);
    return __builtin_bit_cast(short, h);
}

// async global->LDS, 16B per lane; LDS dest = wave-uniform base + lane*16
#define GLDS16(SRC, DST) __builtin_amdgcn_global_load_lds( \
    (__attribute__((address_space(1))) void*)(SRC),        \
    (__attribute__((address_space(3))) void*)(DST), 16, 0, 0)

// ---------------------------------------------------------------------------
// K1: GroupNorm partial sums (blocks 0..255)  +  weight transpose to bf16
//     (blocks 256..1279) fused into one launch.
// ---------------------------------------------------------------------------
__global__ __launch_bounds__(256) void gn_part_prep(const float* __restrict__ x,
                                                    float* __restrict__ part,
                                                    const float* __restrict__ wq,
                                                    const float* __restrict__ wk,
                                                    const float* __restrict__ wv,
                                                    const float* __restrict__ wo,
                                                    short* __restrict__ wt) {
    if (blockIdx.x >= 256) {
        const int bb = blockIdx.x - 256;
        const int z = bb >> 8;
        const int n = bb & 255;
        const int k = threadIdx.x;
        const float* w = (z == 0) ? wq : (z == 1) ? wk : (z == 2) ? wv : wo;
        wt[(z * 256 + n) * 256 + k] = f2b(w[k * 256 + n]);
        return;
    }
    const int b = blockIdx.x >> 3, ch = blockIdx.x & 7;
    const int t = threadIdx.x;
    const int c4 = t & 63;
    const int rr = t >> 6;
    float s1 = 0.f, s2 = 0.f;
    for (int i = 0; i < 32; ++i) {
        const int pos = ch * 128 + rr + (i << 2);
        const f32x4 v = *reinterpret_cast<const f32x4*>(x + (((b << 10) + pos) << 8) + (c4 << 2));
        s1 += v[0] + v[1] + v[2] + v[3];
        s2 += v[0]*v[0] + v[1]*v[1] + v[2]*v[2] + v[3]*v[3];
    }
    __shared__ float ls1[256], ls2[256];
    ls1[t] = s1; ls2[t] = s2;
    __syncthreads();
    if (t < 32) {
        float a1 = 0.f, a2 = 0.f;
        for (int r2 = 0; r2 < 4; ++r2)
            for (int e = 0; e < 2; ++e) {
                const int idx = r2 * 64 + t * 2 + e;
                a1 += ls1[idx]; a2 += ls2[idx];
            }
        part[((b * 8 + ch) * 32 + t) * 2 + 0] = a1;
        part[((b * 8 + ch) * 32 + t) * 2 + 1] = a2;
    }
}

// ---------------------------------------------------------------------------
// K2: fused GN-finalize + GN-normalize + QKV projection.
// ---------------------------------------------------------------------------
__global__ __launch_bounds__(256) void qkv_gemm(const float* __restrict__ x,
                                                const float* __restrict__ part,
                                                const float* __restrict__ gns,
                                                const float* __restrict__ gnb,
                                                const short* __restrict__ wt,
                                                const float* __restrict__ bq,
                                                const float* __restrict__ bk,
                                                const float* __restrict__ bv,
                                                short* __restrict__ qo,
                                                short* __restrict__ ko,
                                                short* __restrict__ vtg) {
    __shared__ short At[64][264];
    __shared__ float gmean[32], grstd[32];
    __shared__ float sA[256], sB[256];

    const int t  = threadIdx.x;
    const int m0 = blockIdx.x * 64;
    const int b  = m0 >> 10;
    const int lane = t & 63, w = t >> 6;
    const int lr = lane & 15, lh = lane >> 4;

    if (t < 32) {
        float s1 = 0.f, s2 = 0.f;
        for (int ch = 0; ch < 8; ++ch) {
            s1 += part[((b * 8 + ch) * 32 + t) * 2 + 0];
            s2 += part[((b * 8 + ch) * 32 + t) * 2 + 1];
        }
        const float mean = s1 * (1.f / 8192.f);
        const float var  = s2 * (1.f / 8192.f) - mean * mean;
        gmean[t] = mean;
        grstd[t] = rsqrtf(var + EPSV);
    }
    __syncthreads();
    {
        const float a = grstd[t >> 3] * gns[t];
        sA[t] = a;
        sB[t] = gnb[t] - gmean[t >> 3] * a;
    }
    __syncthreads();

    {
        const int r = t >> 2, q4 = t & 3;
        const float* xrow = x + (m0 + r) * 256;
        for (int i = 0; i < 16; ++i) {
            const int c0 = (q4 + 4 * i) * 4;
            const f32x4 v  = *reinterpret_cast<const f32x4*>(xrow + c0);
            const f32x4 aa = *reinterpret_cast<const f32x4*>(&sA[c0]);
            const f32x4 bb = *reinterpret_cast<const f32x4*>(&sB[c0]);
            s16x4 o;
            for (int j = 0; j < 4; ++j) o[j] = f2b(v[j] * aa[j] + bb[j]);
            *reinterpret_cast<s16x4*>(&At[r][c0]) = o;
        }
    }
    __syncthreads();

    for (int z = 0; z < 3; ++z) {
        f32x4 acc[4][4];
        for (int mi = 0; mi < 4; ++mi)
            for (int ni = 0; ni < 4; ++ni) acc[mi][ni] = (f32x4){0.f, 0.f, 0.f, 0.f};
        const short* wz = wt + z * 65536 + (w * 64 + lr) * 256 + lh * 8;
#pragma unroll
        for (int kt = 0; kt < 8; ++kt) {
            bfrag bf[4];
#pragma unroll
            for (int ni = 0; ni < 4; ++ni)
                bf[ni] = *reinterpret_cast<const bfrag*>(wz + ni * 4096 + kt * 32);
            bfrag af[4];
#pragma unroll
            for (int mi = 0; mi < 4; ++mi)
                af[mi] = *reinterpret_cast<const bfrag*>(&At[mi * 16 + lr][kt * 32 + lh * 8]);
#pragma unroll
            for (int ni = 0; ni < 4; ++ni)
#pragma unroll
                for (int mi = 0; mi < 4; ++mi)
                    acc[mi][ni] = __builtin_amdgcn_mfma_f32_16x16x32_bf16(af[mi], bf[ni], acc[mi][ni], 0, 0, 0);
        }
        if (z == 2) {
            for (int ni = 0; ni < 4; ++ni) {
                const int col = w * 64 + ni * 16 + lr;
                const float bb = bv[col];
                for (int mi = 0; mi < 4; ++mi) {
                    const int pos = (m0 & 1023) + mi * 16 + lh * 4;
                    s16x4 ov;
                    for (int j = 0; j < 4; ++j) ov[j] = f2b(acc[mi][ni][j] + bb);
                    *reinterpret_cast<s16x4*>(&vtg[(((b << 8) + col) << 10) + pos]) = ov;
                }
            }
        } else {
            short* outp = (z == 0) ? qo : ko;
            const float* bias = (z == 0) ? bq : bk;
            const float s = (z == 0) ? QSC : 1.0f;
            for (int ni = 0; ni < 4; ++ni) {
                const int col = w * 64 + ni * 16 + lr;
                const float bsc = bias[col] * s;
                for (int mi = 0; mi < 4; ++mi) {
                    const int row = m0 + mi * 16 + lh * 4;
                    for (int j = 0; j < 4; ++j)
                        outp[(row + j) * 256 + col] = f2b(acc[mi][ni][j] * s + bsc);
                }
            }
        }
    }
}

// ---------------------------------------------------------------------------
// K3: flash attention (proven r5 structure, 68.7us) + FUSED output projection.
// 8 waves (512 thr), QBLK=128, grid 256 (XCD-swizzled) = 1 block/CU.
// Main loop identical to round-5's attn (expf softmax, QSC=1/16, dbuf K/V via
// global_load_lds, counted vmcnt(8), P staged after rescale).
// Epilogue: normalized O (bf16) -> LDS [128][264], then per-block GEMM with
// Wo (L2-hot) + bias + residual -> fp32 out.  Saves ao write+read (32MB) and
// one kernel launch.
// ---------------------------------------------------------------------------
__global__ __launch_bounds__(512) void attn_fused(const short* __restrict__ qq,
                                                  const short* __restrict__ kk,
                                                  const short* __restrict__ vt,
                                                  const short* __restrict__ wto,
                                                  const float* __restrict__ bo,
                                                  const float* __restrict__ x,
                                                  float* __restrict__ out) {
    // One flat LDS pool, carved:
    //   Kt[buf]: L + buf*16384          (2 x 32 KB, 64x256)
    //   Vt[buf]: L + 32768 + buf*16384  (2 x 32 KB, 256x64)
    //   Pl[w]:   L + 65536 + w*1024     (8 x 2 KB, 16x64)
    //   Ot (epilogue alias): L, [128][264] bf16 (67.6 KB)
    __shared__ __align__(1024) short L[73728];   // 144 KB

    int bid = blockIdx.x;
    bid = ((bid & 7) << 5) | (bid >> 3);   // XCD swizzle: 4 batches/XCD in L2
    const int b = bid >> 3, qt = bid & 7;
    const int t = threadIdx.x;
    const int w = t >> 6, lane = t & 63;
    const int lr = lane & 15, lh = lane >> 4;
    const int qr0 = qt * 128 + w * 16;
    const int sw = lr & 7;

    bfrag qf[8];
    {
        const short* qp = qq + (((b << 10) + qr0 + lr) << 8) + lh * 8;
#pragma unroll
        for (int ks = 0; ks < 8; ++ks)
            qf[ks] = *reinterpret_cast<const bfrag*>(qp + ks * 32);
    }

    const short* kbase = kk + ((long)b << 18);
    const short* vbase = vt + ((long)b << 18);
    short* plw = L + 65536 + (w << 10);

    auto stageK = [&](int kt_, int buf) {
#pragma unroll
        for (int t2 = 0; t2 < 4; ++t2) {
            const int rbase = w * 8 + t2 * 2;
            const int r  = rbase + (lane >> 5);
            const int gs = (lane & 31) ^ (r & 7);
            GLDS16(kbase + ((kt_ * 64 + r) << 8) + (gs << 3),
                   &L[buf * 16384 + (rbase << 8)]);
        }
    };
    auto stageV = [&](int kt_, int buf) {
#pragma unroll
        for (int t2 = 0; t2 < 4; ++t2) {
            const int rbase = w * 32 + t2 * 8;
            const int r  = rbase + (lane >> 3);
            const int gs = (lane & 7) ^ (r & 7);
            GLDS16(vbase + (r << 10) + kt_ * 64 + (gs << 3),
                   &L[32768 + buf * 16384 + (rbase << 6)]);
        }
    };

    f32x4 o[16];
#pragma unroll
    for (int ci = 0; ci < 16; ++ci) o[ci] = (f32x4){0.f, 0.f, 0.f, 0.f};
    float m = -3e38f, lsum = 0.f;

    stageK(0, 0); stageV(0, 0);

    for (int kt = 0; kt < 16; ++kt) {
        const int cur = kt & 1;
        __asm__ volatile("s_barrier" ::: "memory");
        if (kt < 15) {
            stageK(kt + 1, cur ^ 1);
            stageV(kt + 1, cur ^ 1);
            __asm__ volatile("s_waitcnt vmcnt(8)" ::: "memory");
        } else {
            __asm__ volatile("s_waitcnt vmcnt(0)" ::: "memory");
        }
        __asm__ volatile("s_barrier" ::: "memory");

        // ---- S^T = K . Q
        f32x4 sacc[4];
#pragma unroll
        for (int ni = 0; ni < 4; ++ni) sacc[ni] = (f32x4){0.f, 0.f, 0.f, 0.f};
        __builtin_amdgcn_s_setprio(1);
#pragma unroll
        for (int ks = 0; ks < 8; ++ks) {
#pragma unroll
            for (int ni = 0; ni < 4; ++ni) {
                const int row = ni * 16 + lr;
                const bfrag kf = *reinterpret_cast<const bfrag*>(
                    &L[cur * 16384 + (row << 8) + ((((ks << 2) + lh) ^ sw) << 3)]);
                sacc[ni] = __builtin_amdgcn_mfma_f32_16x16x32_bf16(kf, qf[ks], sacc[ni], 0, 0, 0);
            }
        }
        __builtin_amdgcn_s_setprio(0);

        // ---- online softmax, per-lane state for q-row lr
        float rm = fmaxf(fmaxf(sacc[0][0], sacc[0][1]), fmaxf(sacc[0][2], sacc[0][3]));
#pragma unroll
        for (int ni = 1; ni < 4; ++ni)
            rm = fmaxf(rm, fmaxf(fmaxf(sacc[ni][0], sacc[ni][1]),
                                 fmaxf(sacc[ni][2], sacc[ni][3])));
        rm = fmaxf(rm, __shfl_xor(rm, 16));
        rm = fmaxf(rm, __shfl_xor(rm, 32));

        const bool grow = __any(rm > m);
        float p[4][4];
        float rs = 0.f;
        if (grow) {
            const float mn = fmaxf(m, rm);
            const float sc = __expf(m - mn);
            m = mn;
#pragma unroll
            for (int ni = 0; ni < 4; ++ni)
#pragma unroll
                for (int r2 = 0; r2 < 4; ++r2) {
                    p[ni][r2] = __expf(sacc[ni][r2] - mn);
                    rs += p[ni][r2];
                }
            rs += __shfl_xor(rs, 16);
            rs += __shfl_xor(rs, 32);
            lsum = lsum * sc + rs;
            float scb[4];
#pragma unroll
            for (int j = 0; j < 4; ++j) scb[j] = __shfl(sc, lh * 4 + j);
#pragma unroll
            for (int ci = 0; ci < 16; ++ci)
#pragma unroll
                for (int j = 0; j < 4; ++j) o[ci][j] *= scb[j];
        } else {
#pragma unroll
            for (int ni = 0; ni < 4; ++ni)
#pragma unroll
                for (int r2 = 0; r2 < 4; ++r2) {
                    p[ni][r2] = __expf(sacc[ni][r2] - m);
                    rs += p[ni][r2];
                }
            rs += __shfl_xor(rs, 16);
            rs += __shfl_xor(rs, 32);
            lsum += rs;
        }

        // ---- stage P
#pragma unroll
        for (int ni = 0; ni < 4; ++ni) {
            s16x4 pw;
#pragma unroll
            for (int r2 = 0; r2 < 4; ++r2) pw[r2] = f2b(p[ni][r2]);
            const int gc = (ni << 1) + (lh >> 1);
            const int ad = (lr << 6) + ((gc ^ sw) << 3) + ((lh & 1) << 2);
            *reinterpret_cast<s16x4*>(&plw[ad]) = pw;
        }
        const bfrag pa0 = *reinterpret_cast<const bfrag*>(
            &plw[(lr << 6) + ((lh ^ sw) << 3)]);
        const bfrag pa1 = *reinterpret_cast<const bfrag*>(
            &plw[(lr << 6) + (((4 + lh) ^ sw) << 3)]);

        // ---- O += P . V
        __builtin_amdgcn_s_setprio(1);
#pragma unroll
        for (int ci = 0; ci < 16; ++ci) {
            const int row = (ci << 4) + lr;
            const bfrag vb0 = *reinterpret_cast<const bfrag*>(
                &L[32768 + cur * 16384 + (row << 6) + ((lh ^ sw) << 3)]);
            const bfrag vb1 = *reinterpret_cast<const bfrag*>(
                &L[32768 + cur * 16384 + (row << 6) + (((4 + lh) ^ sw) << 3)]);
            o[ci] = __builtin_amdgcn_mfma_f32_16x16x32_bf16(pa0, vb0, o[ci], 0, 0, 0);
            o[ci] = __builtin_amdgcn_mfma_f32_16x16x32_bf16(pa1, vb1, o[ci], 0, 0, 0);
        }
        __builtin_amdgcn_s_setprio(0);
    }

    float invb[4];
#pragma unroll
    for (int j = 0; j < 4; ++j) invb[j] = 1.0f / __shfl(lsum, lh * 4 + j);

    // ================= fused output projection =================
    __syncthreads();   // everyone done with Kt/Vt/Pl -> reuse L as Ot[128][264]

    // write normalized O (bf16) into Ot; wave w owns local rows w*16..+15
#pragma unroll
    for (int j = 0; j < 4; ++j) {
        const int rloc = w * 16 + lh * 4 + j;
#pragma unroll
        for (int ci = 0; ci < 16; ++ci)
            L[rloc * 264 + (ci << 4) + lr] = f2b(o[ci][j] * invb[j]);
    }
    __syncthreads();

    // per-block GEMM: Ot[128][256] x Wo^T -> out rows m0r..+127, 8 waves x 32 cols
    const int m0r = (b << 10) + qt * 128;
    f32x4 acc[8][2];
#pragma unroll
    for (int mi = 0; mi < 8; ++mi) {
        acc[mi][0] = (f32x4){0.f, 0.f, 0.f, 0.f};
        acc[mi][1] = (f32x4){0.f, 0.f, 0.f, 0.f};
    }
    const short* wz = wto + (w * 32 + lr) * 256 + lh * 8;
#pragma unroll
    for (int kt = 0; kt < 8; ++kt) {
        bfrag bf[2];
#pragma unroll
        for (int ni = 0; ni < 2; ++ni)
            bf[ni] = *reinterpret_cast<const bfrag*>(wz + ni * 4096 + kt * 32);
        bfrag af[8];
#pragma unroll
        for (int mi = 0; mi < 8; ++mi)
            af[mi] = *reinterpret_cast<const bfrag*>(
                &L[(mi * 16 + lr) * 264 + kt * 32 + lh * 8]);
#pragma unroll
        for (int ni = 0; ni < 2; ++ni)
#pragma unroll
            for (int mi = 0; mi < 8; ++mi)
                acc[mi][ni] = __builtin_amdgcn_mfma_f32_16x16x32_bf16(af[mi], bf[ni], acc[mi][ni], 0, 0, 0);
    }

#pragma unroll
    for (int ni = 0; ni < 2; ++ni) {
        const int col = w * 32 + ni * 16 + lr;
        const float bb = bo[col];
#pragma unroll
        for (int mi = 0; mi < 8; ++mi) {
            const int row = m0r + mi * 16 + lh * 4;
#pragma unroll
            for (int j = 0; j < 4; ++j) {
                const int idx = (row + j) * 256 + col;
                out[idx] = acc[mi][ni][j] + bb + x[idx];
            }
        }
    }
}

// ---------------------------------------------------------------------------
extern "C" void kernel_launch(void* const* d_in, const int* in_sizes, int n_in,
                              void* d_out, int out_size, void* d_ws, size_t ws_size,
                              hipStream_t stream) {
    const float* x   = (const float*)d_in[0];
    const float* gns = (const float*)d_in[1];
    const float* gnb = (const float*)d_in[2];
    const float* Wq  = (const float*)d_in[3];
    const float* bq  = (const float*)d_in[4];
    const float* Wk  = (const float*)d_in[5];
    const float* bk  = (const float*)d_in[6];
    const float* Wv  = (const float*)d_in[7];
    const float* bv  = (const float*)d_in[8];
    const float* Wo  = (const float*)d_in[9];
    const float* bo  = (const float*)d_in[10];
    float* out = (float*)d_out;

    char* ws = (char*)d_ws;
    short* wt   = (short*)(ws);
    float* part = (float*)(ws + 524288);
    const size_t MB16 = 16777216;
    short* qb  = (short*)(ws + (1 << 20));
    short* kb  = (short*)(ws + (1 << 20) + MB16);
    short* vtb = (short*)(ws + (1 << 20) + 2 * MB16);

    hipLaunchKernelGGL(gn_part_prep, dim3(1280), dim3(256), 0, stream,
                       x, part, Wq, Wk, Wv, Wo, wt);
    hipLaunchKernelGGL(qkv_gemm, dim3(512), dim3(256), 0, stream,
                       x, part, gns, gnb, wt, bq, bk, bv, qb, kb, vtb);
    hipLaunchKernelGGL(attn_fused, dim3(256), dim3(512), 0, stream,
                       qb, kb, vtb, wt + 3 * 65536, bo, x, out);
}